// Round 2
// baseline (147.915 us; speedup 1.0000x reference)
//
#include <hip/hip_runtime.h>

// TurnEmbedding: out[b,s,o] = sum_t sum_p turns[token_ids[b,s], t]^p * poly_coeffs[t,p,o]
// BATCH=32 SEQ=8192 VOCAB=50257 N_TURNS=4 P=4 OUT_DIM=128
//
// Write-bound: 134 MB fp32 out vs ~5 MB reads -> kernel floor ~21 us @6.6 TB/s
// (fill-measured rate). Replay additionally carries harness poisons (537 MB ws
// fill ~80 us + 134 MB out fill ~20 us) -> ~123 us replay traffic floor.
//
// R6 post-mortem: 4x VALU reduction (LDS poly table) was NEUTRAL -> kernel is
// not VALU-bound (per-CU VALU = 128 lanes/cyc; Horner was only ~5 us vs 21 us
// stores). R7: remove ALL remaining non-store structure -- no LDS, no
// __syncthreads, no gather phase, 0 LDS -> full 8 blocks/CU residency. The 32
// lanes of a token issue same-address loads (hardware-coalesced broadcast;
// turns = 804 KB is L2/L3-hot, token_ids streamed once). All 16 id-loads are
// hoisted so gather latency pipelines under the store stream. This is the
// closest a correct kernel gets to fillBuffer; if it's neutral too, the
// kernel is at the write roofline and the residual is fixed harness overhead.

constexpr int N_TOKENS = 32 * 8192;   // 262144
constexpr int OUT_DIM  = 128;
constexpr int N_TURNS  = 4;

constexpr int BLOCK         = 256;
constexpr int GRID          = 2048;
constexpr int TOK_PER_BLOCK = N_TOKENS / GRID;              // 128
constexpr int TOK_PER_ITER  = BLOCK / 32;                   // 8
constexpr int ITERS         = TOK_PER_BLOCK / TOK_PER_ITER; // 16

typedef float floatx4 __attribute__((ext_vector_type(4)));

__device__ __forceinline__ floatx4 f4_fma(float a, const floatx4 b, const floatx4 c) {
    floatx4 r;
    r.x = fmaf(a, b.x, c.x);
    r.y = fmaf(a, b.y, c.y);
    r.z = fmaf(a, b.z, c.z);
    r.w = fmaf(a, b.w, c.w);
    return r;
}

__global__ __launch_bounds__(BLOCK) void TurnEmbedding_50053548867731_kernel(
    const int*     __restrict__ token_ids,   // (N_TOKENS)
    const floatx4* __restrict__ turns,       // (VOCAB) rows, one float4 each
    const float*   __restrict__ coeffs,      // (N_TURNS, P=4, OUT_DIM)
    floatx4*       __restrict__ out)         // (N_TOKENS, OUT_DIM/4)
{
    const int tid   = threadIdx.x;
    const int slot  = tid >> 5;     // 0..7 : token slot within iteration
    const int o4    = tid & 31;     // which float4 of the 32 per token
    const int base0 = blockIdx.x * TOK_PER_BLOCK;

    // Hoist all 16 token-id loads (static-indexed, fully unrolled -> registers;
    // issues 16 independent loads, 2 distinct addresses per wave, L2-hot).
    int ids[ITERS];
#pragma unroll
    for (int it = 0; it < ITERS; ++it)
        ids[it] = token_ids[base0 + it * TOK_PER_ITER + slot];

    // Loop-invariant coefficients (2 KB, same addresses for every block ->
    // L2-broadcast-hot). Degree-0 terms folded into one sum.
    floatx4 c1[N_TURNS], c2[N_TURNS], c3[N_TURNS];
    floatx4 c0sum = (floatx4)(0.f);
#pragma unroll
    for (int t = 0; t < N_TURNS; ++t) {
        const float* base_t = coeffs + (t * 4) * OUT_DIM + o4 * 4;
        c0sum = c0sum + *reinterpret_cast<const floatx4*>(base_t + 0 * OUT_DIM);
        c1[t] = *reinterpret_cast<const floatx4*>(base_t + 1 * OUT_DIM);
        c2[t] = *reinterpret_cast<const floatx4*>(base_t + 2 * OUT_DIM);
        c3[t] = *reinterpret_cast<const floatx4*>(base_t + 3 * OUT_DIM);
    }

    // Pure streaming loop: broadcast x4 load (same addr across 32 lanes,
    // L2/L3-resident), 12 f4-FMAs, coalesced float4 store. No LDS, no barrier.
#pragma unroll
    for (int it = 0; it < ITERS; ++it) {
        const int t_local = it * TOK_PER_ITER + slot;
        const floatx4 x4 = turns[ids[it]];
        const float xv[N_TURNS] = {x4.x, x4.y, x4.z, x4.w};

        floatx4 acc = c0sum;
#pragma unroll
        for (int t = 0; t < N_TURNS; ++t) {
            const float x = xv[t];
            floatx4 r = f4_fma(x, c3[t], c2[t]);
            r = f4_fma(x, r, c1[t]);
            acc = f4_fma(x, r, acc);
        }

        out[(base0 + t_local) * (OUT_DIM / 4) + o4] = acc;
    }
}

extern "C" void kernel_launch(void* const* d_in, const int* in_sizes, int n_in,
                              void* d_out, int out_size, void* d_ws, size_t ws_size,
                              hipStream_t stream) {
    const int*   token_ids = (const int*)d_in[0];
    const float* turns     = (const float*)d_in[1];
    const float* coeffs    = (const float*)d_in[2];

    TurnEmbedding_50053548867731_kernel<<<GRID, BLOCK, 0, stream>>>(
        token_ids,
        reinterpret_cast<const floatx4*>(turns),
        coeffs,
        reinterpret_cast<floatx4*>(d_out));
}

// Round 3
// 146.402 us; speedup vs baseline: 1.0103x; 1.0103x over previous
//
#include <hip/hip_runtime.h>

// TurnEmbedding: out[b,s,o] = sum_t sum_p turns[token_ids[b,s], t]^p * poly_coeffs[t,p,o]
// BATCH=32 SEQ=8192 VOCAB=50257 N_TURNS=4 P=4 OUT_DIM=128
//
// Write-bound: 134 MB fp32 out vs ~5 MB reads -> kernel floor ~21 us @6.6 TB/s.
// Replay also carries harness poisons (537 MB ws fill ~80 us + 134 MB out fill
// ~20 us) -> ~123 us replay traffic floor.
//
// R7 post-mortem: dropping LDS/barrier REGRESSED 8 us (VGPR pressure from 16
// hoisted gathers cut blocks/CU -> worse store-latency hiding). Kernel time is
// still structure-sensitive, so not yet at the roofline. R8 keeps R5's proven
// two-phase core (best: 139.8) and attacks the two features R5/R6 shared:
//   1. static single-cohort schedule (2048x256 = exactly 32 waves/CU, no
//      refill; gather heads lockstep at t=0, drain tail at end)
//      -> GRID 4096, 64 tok/block: half the cohort queued, dynamic refill
//         overlaps fresh blocks' gathers with resident blocks' stores.
//   2. 134 MB of stores churning through L2 alongside the turns gather set
//      -> non-temporal stores (global_store_dwordx4 nt) stream past L2.

constexpr int N_TOKENS = 32 * 8192;   // 262144
constexpr int OUT_DIM  = 128;
constexpr int N_TURNS  = 4;

constexpr int BLOCK         = 256;
constexpr int GRID          = 4096;
constexpr int TOK_PER_BLOCK = N_TOKENS / GRID;              // 64
constexpr int TOK_PER_ITER  = BLOCK / 32;                   // 8
constexpr int ITERS         = TOK_PER_BLOCK / TOK_PER_ITER; // 8

typedef float floatx4 __attribute__((ext_vector_type(4)));

__device__ __forceinline__ floatx4 f4_fma(float a, const floatx4 b, const floatx4 c) {
    floatx4 r;
    r.x = fmaf(a, b.x, c.x);
    r.y = fmaf(a, b.y, c.y);
    r.z = fmaf(a, b.z, c.z);
    r.w = fmaf(a, b.w, c.w);
    return r;
}

__global__ __launch_bounds__(BLOCK) void TurnEmbedding_50053548867731_kernel(
    const int*     __restrict__ token_ids,   // (N_TOKENS)
    const floatx4* __restrict__ turns,       // (VOCAB) rows, one float4 each
    const float*   __restrict__ coeffs,      // (N_TURNS, P=4, OUT_DIM)
    floatx4*       __restrict__ out)         // (N_TOKENS, OUT_DIM/4)
{
    __shared__ floatx4 xbuf[TOK_PER_BLOCK];  // 1 KB

    const int tid   = threadIdx.x;
    const int slot  = tid >> 5;     // 0..7 : token slot within iteration
    const int o4    = tid & 31;     // which float4 of the 32 per token
    const int base0 = blockIdx.x * TOK_PER_BLOCK;

    // Phase 1: burst-gather the block's 64 token vectors into LDS.
    // 64 independent id-loads then 64 independent 16B gathers in flight,
    // ONE latency hop per block.
    if (tid < TOK_PER_BLOCK) {
        const int id = token_ids[base0 + tid];
        xbuf[tid] = turns[id];
    }

    // Loop-invariant coefficients (2 KB, same for every block -> L2-hot).
    // Degree-0 terms folded into one sum. Overlaps with phase-1 latency.
    floatx4 c1[N_TURNS], c2[N_TURNS], c3[N_TURNS];
    floatx4 c0sum = (floatx4)(0.f);
#pragma unroll
    for (int t = 0; t < N_TURNS; ++t) {
        const float* base_t = coeffs + (t * 4) * OUT_DIM + o4 * 4;
        c0sum = c0sum + *reinterpret_cast<const floatx4*>(base_t + 0 * OUT_DIM);
        c1[t] = *reinterpret_cast<const floatx4*>(base_t + 1 * OUT_DIM);
        c2[t] = *reinterpret_cast<const floatx4*>(base_t + 2 * OUT_DIM);
        c3[t] = *reinterpret_cast<const floatx4*>(base_t + 3 * OUT_DIM);
    }

    __syncthreads();

    // Phase 2: pure streaming expansion. LDS broadcast read (same address
    // within half-wave -> conflict-free), 12 f4-FMAs, non-temporal coalesced
    // float4 store (out is written once, never read -> stream past L2).
#pragma unroll
    for (int it = 0; it < ITERS; ++it) {
        const int t_local = it * TOK_PER_ITER + slot;
        const floatx4 x4 = xbuf[t_local];
        const float xv[N_TURNS] = {x4.x, x4.y, x4.z, x4.w};

        floatx4 acc = c0sum;
#pragma unroll
        for (int t = 0; t < N_TURNS; ++t) {
            const float x = xv[t];
            floatx4 r = f4_fma(x, c3[t], c2[t]);
            r = f4_fma(x, r, c1[t]);
            acc = f4_fma(x, r, acc);
        }

        __builtin_nontemporal_store(acc, &out[(base0 + t_local) * (OUT_DIM / 4) + o4]);
    }
}

extern "C" void kernel_launch(void* const* d_in, const int* in_sizes, int n_in,
                              void* d_out, int out_size, void* d_ws, size_t ws_size,
                              hipStream_t stream) {
    const int*   token_ids = (const int*)d_in[0];
    const float* turns     = (const float*)d_in[1];
    const float* coeffs    = (const float*)d_in[2];

    TurnEmbedding_50053548867731_kernel<<<GRID, BLOCK, 0, stream>>>(
        token_ids,
        reinterpret_cast<const floatx4*>(turns),
        coeffs,
        reinterpret_cast<floatx4*>(d_out));
}

// Round 4
// 140.539 us; speedup vs baseline: 1.0525x; 1.0417x over previous
//
#include <hip/hip_runtime.h>

// TurnEmbedding: out[b,s,o] = sum_t sum_p turns[token_ids[b,s], t]^p * poly_coeffs[t,p,o]
// BATCH=32 SEQ=8192 VOCAB=50257 N_TURNS=4 P=4 OUT_DIM=128
//
// Write-bound: 134 MB fp32 out vs ~5 MB reads. Kernel floor ~21 us @6.6 TB/s.
// Replay also carries harness poisons (537 MB ws fill ~80 us + 134 MB out
// fill ~20 us) -> ~123 us replay traffic floor.
//
// FINAL (R9 = R5 restored). Plateau evidence, normalized by same-run ws-fill
// (fills vary +-8% run to run; residual = dur_us - ws_fill):
//   R5 two-phase LDS       residual 60.4 us   <- this kernel (best raw: 139.6/139.8)
//   R6 LDS poly-table (4x less VALU)   60.6   neutral
//   R8 grid-refill + nt stores         60.2   neutral
//   R7 no-LDS hoisted-gather           67.1   regressed (VGPR pressure)
// Three structurally disjoint kernels tie within 0.7% -> kernel is at its
// write roofline; the remaining residual is out-fill (~21 us) + fixed
// harness reset dispatches. No kernel-side lever (compute, LDS volume,
// occupancy refill, L2 bypass) moves it.
//
// Structure: phase 1 gathers the block's 128 turn vectors into LDS in one
// burst (128 independent loads in flight, ONE latency hop per block).
// Phase 2 is a pure store stream: broadcast LDS read (same address within
// half-wave -> conflict-free), 12 f4-FMAs, coalesced float4 store.

constexpr int N_TOKENS = 32 * 8192;   // 262144
constexpr int OUT_DIM  = 128;
constexpr int N_TURNS  = 4;

constexpr int BLOCK         = 256;
constexpr int GRID          = 2048;
constexpr int TOK_PER_BLOCK = N_TOKENS / GRID;              // 128
constexpr int TOK_PER_ITER  = BLOCK / 32;                   // 8
constexpr int ITERS         = TOK_PER_BLOCK / TOK_PER_ITER; // 16

typedef float floatx4 __attribute__((ext_vector_type(4)));

__device__ __forceinline__ floatx4 f4_fma(float a, const floatx4 b, const floatx4 c) {
    floatx4 r;
    r.x = fmaf(a, b.x, c.x);
    r.y = fmaf(a, b.y, c.y);
    r.z = fmaf(a, b.z, c.z);
    r.w = fmaf(a, b.w, c.w);
    return r;
}

__global__ __launch_bounds__(BLOCK) void TurnEmbedding_50053548867731_kernel(
    const int*     __restrict__ token_ids,   // (N_TOKENS)
    const floatx4* __restrict__ turns,       // (VOCAB) rows, one float4 each
    const float*   __restrict__ coeffs,      // (N_TURNS, P=4, OUT_DIM)
    floatx4*       __restrict__ out)         // (N_TOKENS, OUT_DIM/4)
{
    __shared__ floatx4 xbuf[TOK_PER_BLOCK];  // 2 KB

    const int tid   = threadIdx.x;
    const int slot  = tid >> 5;     // 0..7 : token slot within iteration
    const int o4    = tid & 31;     // which float4 of the 32 per token
    const int base0 = blockIdx.x * TOK_PER_BLOCK;

    // Phase 1: burst-gather all 128 token vectors for this block into LDS.
    // 128 independent id-loads then 128 independent 16B gathers in flight.
    if (tid < TOK_PER_BLOCK) {
        const int id = token_ids[base0 + tid];
        xbuf[tid] = turns[id];
    }

    // Loop-invariant coefficients (overlaps with phase-1 latency).
    // Degree-0 terms folded into one sum.
    floatx4 c1[N_TURNS], c2[N_TURNS], c3[N_TURNS];
    floatx4 c0sum = (floatx4)(0.f);
#pragma unroll
    for (int t = 0; t < N_TURNS; ++t) {
        const float* base_t = coeffs + (t * 4) * OUT_DIM + o4 * 4;
        c0sum = c0sum + *reinterpret_cast<const floatx4*>(base_t + 0 * OUT_DIM);
        c1[t] = *reinterpret_cast<const floatx4*>(base_t + 1 * OUT_DIM);
        c2[t] = *reinterpret_cast<const floatx4*>(base_t + 2 * OUT_DIM);
        c3[t] = *reinterpret_cast<const floatx4*>(base_t + 3 * OUT_DIM);
    }

    __syncthreads();

    // Phase 2: pure streaming expansion. No global loads in the loop.
#pragma unroll
    for (int it = 0; it < ITERS; ++it) {
        const int t_local = it * TOK_PER_ITER + slot;
        const floatx4 x4 = xbuf[t_local];     // LDS broadcast, conflict-free
        const float xv[N_TURNS] = {x4.x, x4.y, x4.z, x4.w};

        floatx4 acc = c0sum;
#pragma unroll
        for (int t = 0; t < N_TURNS; ++t) {
            const float x = xv[t];
            floatx4 r = f4_fma(x, c3[t], c2[t]);
            r = f4_fma(x, r, c1[t]);
            acc = f4_fma(x, r, acc);
        }

        out[(base0 + t_local) * (OUT_DIM / 4) + o4] = acc;
    }
}

extern "C" void kernel_launch(void* const* d_in, const int* in_sizes, int n_in,
                              void* d_out, int out_size, void* d_ws, size_t ws_size,
                              hipStream_t stream) {
    const int*   token_ids = (const int*)d_in[0];
    const float* turns     = (const float*)d_in[1];
    const float* coeffs    = (const float*)d_in[2];

    TurnEmbedding_50053548867731_kernel<<<GRID, BLOCK, 0, stream>>>(
        token_ids,
        reinterpret_cast<const floatx4*>(turns),
        coeffs,
        reinterpret_cast<floatx4*>(d_out));
}